// Round 1
// baseline (4243.468 us; speedup 1.0000x reference)
//
#include <hip/hip_runtime.h>

#define NN 50000
#define NH 100000
#define NI 600000
#define FIN 512
#define HID 128
#define LNEPS 1e-5f

// ============================ CSR build ============================
__global__ void k_hist(const int* __restrict__ idx, int n, int* __restrict__ deg) {
  int i = blockIdx.x * 256 + threadIdx.x;
  if (i < n) atomicAdd(&deg[idx[i]], 1);
}

__global__ __launch_bounds__(1024) void k_scan1(int* __restrict__ data, int m,
                                                int* __restrict__ bsums) {
  __shared__ int sh[1024];
  int tid = threadIdx.x;
  int i = blockIdx.x * 1024 + tid;
  int v = (i < m) ? data[i] : 0;
  sh[tid] = v;
  __syncthreads();
  for (int off = 1; off < 1024; off <<= 1) {
    int tv = (tid >= off) ? sh[tid - off] : 0;
    __syncthreads();
    sh[tid] += tv;
    __syncthreads();
  }
  if (i < m) data[i] = sh[tid] - v;  // exclusive
  if (tid == 1023) bsums[blockIdx.x] = sh[1023];
}

__global__ __launch_bounds__(1024) void k_scan2(int* __restrict__ bsums, int nb) {
  __shared__ int sh[1024];
  int tid = threadIdx.x;
  int v = (tid < nb) ? bsums[tid] : 0;
  sh[tid] = v;
  __syncthreads();
  for (int off = 1; off < 1024; off <<= 1) {
    int tv = (tid >= off) ? sh[tid - off] : 0;
    __syncthreads();
    sh[tid] += tv;
    __syncthreads();
  }
  if (tid < nb) bsums[tid] = sh[tid] - v;
}

__global__ void k_scan3(int* __restrict__ data, const int* __restrict__ bsums,
                        int m, int total) {
  int i = blockIdx.x * 256 + threadIdx.x;
  if (i < m) data[i] += bsums[i >> 10];
  if (i == 0) data[m] = total;
}

__global__ void k_fill(const int* __restrict__ key, const int* __restrict__ oth, int n,
                       const int* __restrict__ starts, int* __restrict__ cursor,
                       int* __restrict__ out_oth, int* __restrict__ out_key) {
  int i = blockIdx.x * 256 + threadIdx.x;
  if (i >= n) return;
  int k = key[i];
  int pos = starts[k] + atomicAdd(&cursor[k], 1);
  out_oth[pos] = oth[i];
  if (out_key) out_key[pos] = k;
}

// ============================ small GEMMs ============================
// A (N x K) @ W (K x 128) + bias -> out (N x 128); optional relu; optional dup store.
// blockDim = 128 (one thread per output column), TM rows per block.
template <int K, int TM, bool RELU>
__global__ __launch_bounds__(128) void k_gemm_rows(
    const float* __restrict__ A, const float* __restrict__ W,
    const float* __restrict__ bias, float* __restrict__ out,
    float* __restrict__ out2, int N) {
  __shared__ float Ash[TM][K];
  const int t = threadIdx.x;
  const int r0 = blockIdx.x * TM;
  const int nf4 = TM * K / 4;
  const float4* Ag = reinterpret_cast<const float4*>(A + (size_t)r0 * K);
  float4* As4 = reinterpret_cast<float4*>(&Ash[0][0]);
  for (int f = t; f < nf4; f += 128) As4[f] = Ag[f];
  __syncthreads();
  float acc[TM];
#pragma unroll
  for (int r = 0; r < TM; r++) acc[r] = 0.f;
  for (int k = 0; k < K; k++) {
    float wv = W[k * 128 + t];
#pragma unroll
    for (int r = 0; r < TM; r++) acc[r] += Ash[r][k] * wv;
  }
  float b = bias[t];
  for (int r = 0; r < TM; r++) {
    float v = acc[r] + b;
    if (RELU) v = fmaxf(v, 0.f);
    out[(size_t)(r0 + r) * 128 + t] = v;
    if (out2) out2[(size_t)(r0 + r) * 128 + t] = v;
  }
}

// ============================ LayerNorm (width 128) ============================
__global__ __launch_bounds__(256) void k_ln128(const float* __restrict__ in,
                                               const float* __restrict__ g,
                                               const float* __restrict__ b,
                                               float* __restrict__ out, int N) {
  int wave = threadIdx.x >> 6, lane = threadIdx.x & 63;
  int row = blockIdx.x * 4 + wave;
  if (row >= N) return;
  float2 x = reinterpret_cast<const float2*>(in + (size_t)row * 128)[lane];
  float s = x.x + x.y, sq = x.x * x.x + x.y * x.y;
  for (int m = 1; m < 64; m <<= 1) { s += __shfl_xor(s, m); sq += __shfl_xor(sq, m); }
  float mu = s * (1.f / 128.f);
  float var = sq * (1.f / 128.f) - mu * mu;
  float rstd = rsqrtf(var + LNEPS);
  float2 gg = reinterpret_cast<const float2*>(g)[lane];
  float2 bb = reinterpret_cast<const float2*>(b)[lane];
  float2 o;
  o.x = (x.x - mu) * rstd * gg.x + bb.x;
  o.y = (x.y - mu) * rstd * gg.y + bb.y;
  reinterpret_cast<float2*>(out + (size_t)row * 128)[lane] = o;
}

// blend (0.5*Xv/deg + 0.5*X0) then LN(128)
__global__ __launch_bounds__(256) void k_blend_ln(
    const float* __restrict__ Xv, const int* __restrict__ starts_v,
    const float* __restrict__ X0, const float* __restrict__ g,
    const float* __restrict__ b, float* __restrict__ out, int N) {
  int wave = threadIdx.x >> 6, lane = threadIdx.x & 63;
  int row = blockIdx.x * 4 + wave;
  if (row >= N) return;
  int deg = starts_v[row + 1] - starts_v[row];
  float inv = deg > 0 ? 1.f / (float)deg : 0.f;
  float2 xv = reinterpret_cast<const float2*>(Xv + (size_t)row * 128)[lane];
  float2 x0 = reinterpret_cast<const float2*>(X0 + (size_t)row * 128)[lane];
  float ax = 0.5f * (xv.x * inv) + 0.5f * x0.x;
  float ay = 0.5f * (xv.y * inv) + 0.5f * x0.y;
  float s = ax + ay, sq = ax * ax + ay * ay;
  for (int m = 1; m < 64; m <<= 1) { s += __shfl_xor(s, m); sq += __shfl_xor(sq, m); }
  float mu = s * (1.f / 128.f);
  float var = sq * (1.f / 128.f) - mu * mu;
  float rstd = rsqrtf(var + LNEPS);
  float2 gg = reinterpret_cast<const float2*>(g)[lane];
  float2 bb = reinterpret_cast<const float2*>(b)[lane];
  float2 o;
  o.x = (ax - mu) * rstd * gg.x + bb.x;
  o.y = (ay - mu) * rstd * gg.y + bb.y;
  reinterpret_cast<float2*>(out + (size_t)row * 128)[lane] = o;
}

// ============================ hedge scatter-mean ============================
// Xe[m] = mean over CSR_e incidences of Y[v]; one wave per hedge.
__global__ __launch_bounds__(256) void k_xe(const float* __restrict__ Y,
                                            const int* __restrict__ starts,
                                            const int* __restrict__ vlist,
                                            float* __restrict__ Xe, int M) {
  int wave = threadIdx.x >> 6, lane = threadIdx.x & 63;
  int m = blockIdx.x * 4 + wave;
  if (m >= M) return;
  int s = starts[m], e = starts[m + 1];
  float2 acc = {0.f, 0.f};
  for (int j = s; j < e; j++) {
    int vv = vlist[j];
    float2 val = reinterpret_cast<const float2*>(Y + (size_t)vv * 128)[lane];
    acc.x += val.x;
    acc.y += val.y;
  }
  int d = e - s;
  float inv = d > 0 ? 1.f / (float)d : 0.f;
  float2 o = {acc.x * inv, acc.y * inv};
  reinterpret_cast<float2*>(Xe + (size_t)m * 128)[lane] = o;
}

// ============================ fused W2 stage ============================
// Per block: 32 incidences (v-sorted). Gather [X[v], Xe[e]] -> LDS, LN(256),
// tiled GEMM with w2 (256x128) staged in LDS chunks, segmented-reduce into Xv_sum.
#define TI 32
__global__ __launch_bounds__(256) void k_w2(
    const float* __restrict__ X, const float* __restrict__ Xe,
    const int* __restrict__ v_sorted, const int* __restrict__ e_by_v,
    const float* __restrict__ g2, const float* __restrict__ b2,
    const float* __restrict__ W2, const float* __restrict__ bias2,
    float* __restrict__ Xv_sum) {
  __shared__ float Ash[TI][260];   // 256-wide rows, padded (bank-conflict-free)
  __shared__ float Wsh[32][128];
  __shared__ float gsh[256], bsh[256];
  __shared__ int vs[TI], es[TI];
  const int t = threadIdx.x;
  const int p0 = blockIdx.x * TI;
  if (t < TI) { vs[t] = v_sorted[p0 + t]; es[t] = e_by_v[p0 + t]; }
  gsh[t] = g2[t];
  bsh[t] = b2[t];
  __syncthreads();
  // gather A tile: row = [X[v], Xe[e]]; one wave loads one full 256-float row
  for (int f = t; f < TI * 64; f += 256) {
    int row = f >> 6, c4 = f & 63;
    const float* src = (c4 < 32) ? (X + (size_t)vs[row] * 128 + c4 * 4)
                                 : (Xe + (size_t)es[row] * 128 + (c4 - 32) * 4);
    *reinterpret_cast<float4*>(&Ash[row][c4 * 4]) =
        *reinterpret_cast<const float4*>(src);
  }
  __syncthreads();
  // LN per row (4 waves x 8 rows)
  {
    int wave = t >> 6, lane = t & 63;
    for (int rr = 0; rr < TI / 4; rr++) {
      int row = wave * (TI / 4) + rr;
      float4 xv = *reinterpret_cast<float4*>(&Ash[row][lane * 4]);
      float s = xv.x + xv.y + xv.z + xv.w;
      float sq = xv.x * xv.x + xv.y * xv.y + xv.z * xv.z + xv.w * xv.w;
      for (int m = 1; m < 64; m <<= 1) { s += __shfl_xor(s, m); sq += __shfl_xor(sq, m); }
      float mu = s * (1.f / 256.f);
      float var = sq * (1.f / 256.f) - mu * mu;
      float rstd = rsqrtf(var + LNEPS);
      int k0 = lane * 4;
      float4 o;
      o.x = (xv.x - mu) * rstd * gsh[k0 + 0] + bsh[k0 + 0];
      o.y = (xv.y - mu) * rstd * gsh[k0 + 1] + bsh[k0 + 1];
      o.z = (xv.z - mu) * rstd * gsh[k0 + 2] + bsh[k0 + 2];
      o.w = (xv.w - mu) * rstd * gsh[k0 + 3] + bsh[k0 + 3];
      *reinterpret_cast<float4*>(&Ash[row][lane * 4]) = o;
    }
  }
  __syncthreads();
  // tiled GEMM: thread -> rows tr*4..+3, cols tc*4..+3
  float acc[4][4] = {};
  const int tc = t & 31, tr = t >> 5;
  for (int kk = 0; kk < 8; kk++) {
    for (int f = t; f < 32 * 32; f += 256) {  // 1024 float4 = 32x128 chunk
      int row = f >> 5, c4 = f & 31;
      *reinterpret_cast<float4*>(&Wsh[row][c4 * 4]) =
          *reinterpret_cast<const float4*>(W2 + (size_t)(kk * 32 + row) * 128 + c4 * 4);
    }
    __syncthreads();
    for (int k = 0; k < 32; k++) {
      float4 wv = *reinterpret_cast<const float4*>(&Wsh[k][tc * 4]);
#pragma unroll
      for (int r = 0; r < 4; r++) {
        float av = Ash[tr * 4 + r][kk * 32 + k];
        acc[r][0] += av * wv.x;
        acc[r][1] += av * wv.y;
        acc[r][2] += av * wv.z;
        acc[r][3] += av * wv.w;
      }
    }
    __syncthreads();
  }
  // bias + write Z to LDS (reuse Ash region), then segmented reduce by v
  float* Zsh = &Ash[0][0];  // TI*128 floats fits in TI*260
#pragma unroll
  for (int r = 0; r < 4; r++) {
    int row = tr * 4 + r;
    float4 zv;
    zv.x = acc[r][0] + bias2[tc * 4 + 0];
    zv.y = acc[r][1] + bias2[tc * 4 + 1];
    zv.z = acc[r][2] + bias2[tc * 4 + 2];
    zv.w = acc[r][3] + bias2[tc * 4 + 3];
    *reinterpret_cast<float4*>(&Zsh[row * 128 + tc * 4]) = zv;
  }
  __syncthreads();
  if (t < 128) {
    float a = 0.f;
    for (int r = 0; r < TI; r++) {
      a += Zsh[r * 128 + t];
      if (r == TI - 1 || vs[r + 1] != vs[r]) {
        atomicAdd(&Xv_sum[(size_t)vs[r] * 128 + t], a);
        a = 0.f;
      }
    }
  }
}

// ============================ classifier ============================
__global__ __launch_bounds__(128) void k_cls(
    const float* __restrict__ X, const float* __restrict__ W1,
    const float* __restrict__ b1, const float* __restrict__ lg,
    const float* __restrict__ lb, const float* __restrict__ W2,
    const float* __restrict__ b2, float* __restrict__ out, int N) {
  __shared__ float xr[128];
  int n = blockIdx.x, t = threadIdx.x;
  xr[t] = X[(size_t)n * 128 + t];
  __syncthreads();
  if (t < 64) {
    float a = b1[t];
    for (int k = 0; k < 128; k++) a += xr[k] * W1[k * 64 + t];
    float h = fmaxf(a, 0.f);
    float s = h, sq = h * h;
    for (int m = 1; m < 64; m <<= 1) { s += __shfl_xor(s, m); sq += __shfl_xor(sq, m); }
    float mu = s * (1.f / 64.f);
    float var = sq * (1.f / 64.f) - mu * mu;
    float rstd = rsqrtf(var + LNEPS);
    float hn = (h - mu) * rstd * lg[t] + lb[t];
    float c = hn * W2[t];
    for (int m = 1; m < 64; m <<= 1) c += __shfl_xor(c, m);
    if (t == 0) out[n] = c + b2[0];
  }
}

// ============================ driver ============================
static void run_branch(const float* x_in, const int* v, const int* e,
                       const float* lin_w, const float* lin_b,
                       const float* w1g, const float* w1bn, const float* w1w, const float* w1b,
                       const float* w2g, const float* w2bn, const float* w2w, const float* w2b,
                       const float* wg, const float* wbn, const float* ww, const float* wb,
                       const float* cw1, const float* cb1, const float* cg, const float* cbn,
                       const float* cw2, const float* cb2,
                       float* X, float* X0, float* A, float* B, float* Xe,
                       int* starts_e, int* starts_v, int* cursor, int* bsums,
                       int* v_by_e, int* e_by_v, int* v_sorted,
                       float* out, hipStream_t stream) {
  // CSR by hedge
  hipMemsetAsync(starts_e, 0, (NH + 1) * sizeof(int), stream);
  k_hist<<<(NI + 255) / 256, 256, 0, stream>>>(e, NI, starts_e);
  k_scan1<<<(NH + 1023) / 1024, 1024, 0, stream>>>(starts_e, NH, bsums);
  k_scan2<<<1, 1024, 0, stream>>>(bsums, (NH + 1023) / 1024);
  k_scan3<<<(NH + 255) / 256, 256, 0, stream>>>(starts_e, bsums, NH, NI);
  hipMemsetAsync(cursor, 0, NH * sizeof(int), stream);
  k_fill<<<(NI + 255) / 256, 256, 0, stream>>>(e, v, NI, starts_e, cursor, v_by_e, nullptr);
  // CSR by node
  hipMemsetAsync(starts_v, 0, (NN + 1) * sizeof(int), stream);
  k_hist<<<(NI + 255) / 256, 256, 0, stream>>>(v, NI, starts_v);
  k_scan1<<<(NN + 1023) / 1024, 1024, 0, stream>>>(starts_v, NN, bsums);
  k_scan2<<<1, 1024, 0, stream>>>(bsums, (NN + 1023) / 1024);
  k_scan3<<<(NN + 255) / 256, 256, 0, stream>>>(starts_v, bsums, NN, NI);
  hipMemsetAsync(cursor, 0, NN * sizeof(int), stream);
  k_fill<<<(NI + 255) / 256, 256, 0, stream>>>(v, e, NI, starts_v, cursor, e_by_v, v_sorted);
  // input projection (+relu), duplicated into X and X0
  k_gemm_rows<FIN, 16, true><<<NN / 16, 128, 0, stream>>>(x_in, lin_w, lin_b, X, X0, NN);
  for (int layer = 0; layer < 2; ++layer) {
    k_ln128<<<NN / 4, 256, 0, stream>>>(X, w1g, w1bn, A, NN);
    k_gemm_rows<HID, 16, false><<<NN / 16, 128, 0, stream>>>(A, w1w, w1b, B, nullptr, NN);
    k_xe<<<NH / 4, 256, 0, stream>>>(B, starts_e, v_by_e, Xe, NH);
    hipMemsetAsync(A, 0, (size_t)NN * 128 * sizeof(float), stream);  // A becomes Xv_sum
    k_w2<<<NI / TI, 256, 0, stream>>>(X, Xe, v_sorted, e_by_v, w2g, w2bn, w2w, w2b, A);
    k_blend_ln<<<NN / 4, 256, 0, stream>>>(A, starts_v, X0, wg, wbn, B, NN);
    k_gemm_rows<HID, 16, true><<<NN / 16, 128, 0, stream>>>(B, ww, wb, X, nullptr, NN);
  }
  k_cls<<<NN, 128, 0, stream>>>(X, cw1, cb1, cg, cbn, cw2, cb2, out, NN);
}

extern "C" void kernel_launch(void* const* d_in, const int* in_sizes, int n_in,
                              void* d_out, int out_size, void* d_ws, size_t ws_size,
                              hipStream_t stream) {
  (void)in_sizes; (void)n_in; (void)out_size; (void)ws_size;
  const float* x1 = (const float*)d_in[0];
  const int* v1 = (const int*)d_in[1];
  const int* e1 = (const int*)d_in[2];
  const float* x2 = (const float*)d_in[3];
  const int* v2 = (const int*)d_in[4];
  const int* e2 = (const int*)d_in[5];
  const float* lin_w = (const float*)d_in[6];
  const float* lin_b = (const float*)d_in[7];
  const float* w1g = (const float*)d_in[8];
  const float* w1bn = (const float*)d_in[9];
  const float* w1w = (const float*)d_in[10];
  const float* w1b = (const float*)d_in[11];
  const float* w2g = (const float*)d_in[12];
  const float* w2bn = (const float*)d_in[13];
  const float* w2w = (const float*)d_in[14];
  const float* w2b = (const float*)d_in[15];
  const float* wg = (const float*)d_in[16];
  const float* wbn = (const float*)d_in[17];
  const float* ww = (const float*)d_in[18];
  const float* wb = (const float*)d_in[19];
  const float* cw1 = (const float*)d_in[20];
  const float* cb1 = (const float*)d_in[21];
  const float* cg = (const float*)d_in[22];
  const float* cbn = (const float*)d_in[23];
  const float* cw2 = (const float*)d_in[24];
  const float* cb2 = (const float*)d_in[25];

  char* p = (char*)d_ws;
  auto alloc = [&](size_t bytes) {
    char* r = p;
    p += (bytes + 255) & ~(size_t)255;
    return r;
  };
  float* X = (float*)alloc((size_t)NN * 128 * 4);
  float* X0 = (float*)alloc((size_t)NN * 128 * 4);
  float* A = (float*)alloc((size_t)NN * 128 * 4);   // LN scratch / Xv_sum
  float* B = (float*)alloc((size_t)NN * 128 * 4);
  float* Xe = (float*)alloc((size_t)NH * 128 * 4);
  int* starts_e = (int*)alloc((NH + 1) * 4);
  int* starts_v = (int*)alloc((NN + 1) * 4);
  int* cursor = (int*)alloc(NH * 4);
  int* bsums = (int*)alloc(1024 * 4);
  int* v_by_e = (int*)alloc((size_t)NI * 4);
  int* e_by_v = (int*)alloc((size_t)NI * 4);
  int* v_sorted = (int*)alloc((size_t)NI * 4);

  float* out = (float*)d_out;
  run_branch(x1, v1, e1, lin_w, lin_b, w1g, w1bn, w1w, w1b, w2g, w2bn, w2w, w2b,
             wg, wbn, ww, wb, cw1, cb1, cg, cbn, cw2, cb2,
             X, X0, A, B, Xe, starts_e, starts_v, cursor, bsums,
             v_by_e, e_by_v, v_sorted, out, stream);
  run_branch(x2, v2, e2, lin_w, lin_b, w1g, w1bn, w1w, w1b, w2g, w2bn, w2w, w2b,
             wg, wbn, ww, wb, cw1, cb1, cg, cbn, cw2, cb2,
             X, X0, A, B, Xe, starts_e, starts_v, cursor, bsums,
             v_by_e, e_by_v, v_sorted, out + NN, stream);
}

// Round 3
// 3986.502 us; speedup vs baseline: 1.0645x; 1.0645x over previous
//
#include <hip/hip_runtime.h>

#define NN 50000
#define NH 100000
#define NI 600000
#define FIN 512
#define HID 128
#define LNEPS 1e-5f

typedef __attribute__((ext_vector_type(8))) short short8;
typedef __attribute__((ext_vector_type(4))) short short4v;
typedef __attribute__((ext_vector_type(4))) float f32x4;

static __device__ __forceinline__ short f2bf(float f) {
  unsigned u = __float_as_uint(f);
  unsigned r = (u + 0x7fffu + ((u >> 16) & 1u)) >> 16;
  return (short)r;
}
static __device__ __forceinline__ float bf2f(short h) {
  return __uint_as_float(((unsigned)(unsigned short)h) << 16);
}

// ============================ CSR build ============================
__global__ void k_hist(const int* __restrict__ idx, int n, int* __restrict__ deg) {
  int i = blockIdx.x * 256 + threadIdx.x;
  if (i < n) atomicAdd(&deg[idx[i]], 1);
}

__global__ __launch_bounds__(1024) void k_scan1(int* __restrict__ data, int m,
                                                int* __restrict__ bsums) {
  __shared__ int sh[1024];
  int tid = threadIdx.x;
  int i = blockIdx.x * 1024 + tid;
  int v = (i < m) ? data[i] : 0;
  sh[tid] = v;
  __syncthreads();
  for (int off = 1; off < 1024; off <<= 1) {
    int tv = (tid >= off) ? sh[tid - off] : 0;
    __syncthreads();
    sh[tid] += tv;
    __syncthreads();
  }
  if (i < m) data[i] = sh[tid] - v;  // exclusive
  if (tid == 1023) bsums[blockIdx.x] = sh[1023];
}

__global__ __launch_bounds__(1024) void k_scan2(int* __restrict__ bsums, int nb) {
  __shared__ int sh[1024];
  int tid = threadIdx.x;
  int v = (tid < nb) ? bsums[tid] : 0;
  sh[tid] = v;
  __syncthreads();
  for (int off = 1; off < 1024; off <<= 1) {
    int tv = (tid >= off) ? sh[tid - off] : 0;
    __syncthreads();
    sh[tid] += tv;
    __syncthreads();
  }
  if (tid < nb) bsums[tid] = sh[tid] - v;
}

__global__ void k_scan3(int* __restrict__ data, const int* __restrict__ bsums,
                        int m, int total) {
  int i = blockIdx.x * 256 + threadIdx.x;
  if (i < m) data[i] += bsums[i >> 10];
  if (i == 0) data[m] = total;
}

__global__ void k_fill(const int* __restrict__ key, const int* __restrict__ oth, int n,
                       const int* __restrict__ starts, int* __restrict__ cursor,
                       int* __restrict__ out_oth, int* __restrict__ out_key) {
  int i = blockIdx.x * 256 + threadIdx.x;
  if (i >= n) return;
  int k = key[i];
  int pos = starts[k] + atomicAdd(&cursor[k], 1);
  out_oth[pos] = oth[i];
  if (out_key) out_key[pos] = k;
}

// Sort each CSR segment ascending -> deterministic bucket order every call
// (arrival order from k_fill's atomics is not replay-stable).
__global__ void k_sort_seg(const int* __restrict__ starts, int nseg,
                           int* __restrict__ vals) {
  int seg = blockIdx.x * 256 + threadIdx.x;
  if (seg >= nseg) return;
  int s = starts[seg], e = starts[seg + 1];
  int d = e - s;
  if (d <= 1) return;
  if (d <= 48) {
    int buf[48];
    for (int i = 0; i < d; i++) buf[i] = vals[s + i];
    for (int i = 1; i < d; i++) {
      int key = buf[i], j = i - 1;
      while (j >= 0 && buf[j] > key) { buf[j + 1] = buf[j]; j--; }
      buf[j + 1] = key;
    }
    for (int i = 0; i < d; i++) vals[s + i] = buf[i];
  } else {
    for (int i = s + 1; i < e; i++) {
      int key = vals[i], j = i - 1;
      while (j >= s && vals[j] > key) { vals[j + 1] = vals[j]; j--; }
      vals[j + 1] = key;
    }
  }
}

// ============================ weight conversion ============================
// W2 (256 x 128, k-major) -> hi/lo bf16 pair, [n][k] layout (k contiguous)
__global__ void k_cvt_w2(const float* __restrict__ W2, short* __restrict__ Whi,
                         short* __restrict__ Wlo) {
  int i = blockIdx.x * 256 + threadIdx.x;
  if (i >= 256 * 128) return;
  int n = i & 127, k = i >> 7;
  float w = W2[i];
  short hi = f2bf(w);
  Whi[n * 256 + k] = hi;
  Wlo[n * 256 + k] = f2bf(w - bf2f(hi));
}

// ============================ small GEMMs ============================
template <int K, int TM, bool RELU>
__global__ __launch_bounds__(128) void k_gemm_rows(
    const float* __restrict__ A, const float* __restrict__ W,
    const float* __restrict__ bias, float* __restrict__ out,
    float* __restrict__ out2, int N) {
  __shared__ float Ash[TM][K];
  const int t = threadIdx.x;
  const int r0 = blockIdx.x * TM;
  const int nf4 = TM * K / 4;
  const float4* Ag = reinterpret_cast<const float4*>(A + (size_t)r0 * K);
  float4* As4 = reinterpret_cast<float4*>(&Ash[0][0]);
  for (int f = t; f < nf4; f += 128) As4[f] = Ag[f];
  __syncthreads();
  float acc[TM];
#pragma unroll
  for (int r = 0; r < TM; r++) acc[r] = 0.f;
  for (int k = 0; k < K; k++) {
    float wv = W[k * 128 + t];
#pragma unroll
    for (int r = 0; r < TM; r++) acc[r] += Ash[r][k] * wv;
  }
  float b = bias[t];
  for (int r = 0; r < TM; r++) {
    float v = acc[r] + b;
    if (RELU) v = fmaxf(v, 0.f);
    out[(size_t)(r0 + r) * 128 + t] = v;
    if (out2) out2[(size_t)(r0 + r) * 128 + t] = v;
  }
}

// ============================ LayerNorm (width 128) ============================
__global__ __launch_bounds__(256) void k_ln128(const float* __restrict__ in,
                                               const float* __restrict__ g,
                                               const float* __restrict__ b,
                                               float* __restrict__ out, int N) {
  int wave = threadIdx.x >> 6, lane = threadIdx.x & 63;
  int row = blockIdx.x * 4 + wave;
  if (row >= N) return;
  float2 x = reinterpret_cast<const float2*>(in + (size_t)row * 128)[lane];
  float s = x.x + x.y, sq = x.x * x.x + x.y * x.y;
  for (int m = 1; m < 64; m <<= 1) { s += __shfl_xor(s, m); sq += __shfl_xor(sq, m); }
  float mu = s * (1.f / 128.f);
  float var = sq * (1.f / 128.f) - mu * mu;
  float rstd = rsqrtf(var + LNEPS);
  float2 gg = reinterpret_cast<const float2*>(g)[lane];
  float2 bb = reinterpret_cast<const float2*>(b)[lane];
  float2 o;
  o.x = (x.x - mu) * rstd * gg.x + bb.x;
  o.y = (x.y - mu) * rstd * gg.y + bb.y;
  reinterpret_cast<float2*>(out + (size_t)row * 128)[lane] = o;
}

// blend (0.5*Xv/deg + 0.5*X0) then LN(128)
__global__ __launch_bounds__(256) void k_blend_ln(
    const float* __restrict__ Xv, const int* __restrict__ starts_v,
    const float* __restrict__ X0, const float* __restrict__ g,
    const float* __restrict__ b, float* __restrict__ out, int N) {
  int wave = threadIdx.x >> 6, lane = threadIdx.x & 63;
  int row = blockIdx.x * 4 + wave;
  if (row >= N) return;
  int deg = starts_v[row + 1] - starts_v[row];
  float inv = deg > 0 ? 1.f / (float)deg : 0.f;
  float2 xv = reinterpret_cast<const float2*>(Xv + (size_t)row * 128)[lane];
  float2 x0 = reinterpret_cast<const float2*>(X0 + (size_t)row * 128)[lane];
  float ax = 0.5f * (xv.x * inv) + 0.5f * x0.x;
  float ay = 0.5f * (xv.y * inv) + 0.5f * x0.y;
  float s = ax + ay, sq = ax * ax + ay * ay;
  for (int m = 1; m < 64; m <<= 1) { s += __shfl_xor(s, m); sq += __shfl_xor(sq, m); }
  float mu = s * (1.f / 128.f);
  float var = sq * (1.f / 128.f) - mu * mu;
  float rstd = rsqrtf(var + LNEPS);
  float2 gg = reinterpret_cast<const float2*>(g)[lane];
  float2 bb = reinterpret_cast<const float2*>(b)[lane];
  float2 o;
  o.x = (ax - mu) * rstd * gg.x + bb.x;
  o.y = (ay - mu) * rstd * gg.y + bb.y;
  reinterpret_cast<float2*>(out + (size_t)row * 128)[lane] = o;
}

// ============================ hedge scatter-mean ============================
__global__ __launch_bounds__(256) void k_xe(const float* __restrict__ Y,
                                            const int* __restrict__ starts,
                                            const int* __restrict__ vlist,
                                            float* __restrict__ Xe, int M) {
  int wave = threadIdx.x >> 6, lane = threadIdx.x & 63;
  int m = blockIdx.x * 4 + wave;
  if (m >= M) return;
  int s = starts[m], e = starts[m + 1];
  float2 acc = {0.f, 0.f};
  for (int j = s; j < e; j++) {
    int vv = vlist[j];
    float2 val = reinterpret_cast<const float2*>(Y + (size_t)vv * 128)[lane];
    acc.x += val.x;
    acc.y += val.y;
  }
  int d = e - s;
  float inv = d > 0 ? 1.f / (float)d : 0.f;
  float2 o = {acc.x * inv, acc.y * inv};
  reinterpret_cast<float2*>(Xe + (size_t)m * 128)[lane] = o;
}

// ============================ fused W2 stage (hi/lo bf16 MFMA) ============================
// Per block: 32 incidences (v-sorted, bucket-sorted). Gather [X[v], Xe[e]] to
// registers, wave-shuffle LN(256), split to bf16 hi+lo in LDS, then
// 3x mfma_f32_16x16x32_bf16 (Ahi*Whi + Alo*Whi + Ahi*Wlo) ~= fp32 product.
// Z tile reuses A-tile LDS (barrier in between). Segmented reduce into Xv_sum.
__global__ __launch_bounds__(256) void k_w2(
    const float* __restrict__ X, const float* __restrict__ Xe,
    const int* __restrict__ v_sorted, const int* __restrict__ e_by_v,
    const float* __restrict__ g2, const float* __restrict__ b2,
    const short* __restrict__ Whi, const short* __restrict__ Wlo,
    const float* __restrict__ bias2, float* __restrict__ Xv_sum) {
  __shared__ __align__(16) char smem[2 * 32 * 264 * sizeof(short)];
  short (*Ahi)[264] = (short(*)[264])smem;
  short (*Alo)[264] = (short(*)[264])(smem + 32 * 264 * sizeof(short));
  float (*Zsh)[132] = (float(*)[132])smem;  // reused after MFMA (barrier-protected)
  __shared__ float gsh[256], bsh[256], b2sh[128];
  __shared__ int vs[32], es[32];
  const int t = threadIdx.x;
  const int p0 = blockIdx.x * 32;
  if (t < 32) { vs[t] = v_sorted[p0 + t]; es[t] = e_by_v[p0 + t]; }
  gsh[t] = g2[t];
  bsh[t] = b2[t];
  if (t < 128) b2sh[t] = bias2[t];
  __syncthreads();
  const int wv = t >> 6, lane = t & 63;
  // gather + LN + hi/lo bf16 split: wave wv owns rows wv*8..wv*8+7
  for (int rr = 0; rr < 8; rr++) {
    int row = wv * 8 + rr;
    const float* src = (lane < 32) ? (X + (size_t)vs[row] * 128 + lane * 4)
                                   : (Xe + (size_t)es[row] * 128 + (lane - 32) * 4);
    float4 x = *reinterpret_cast<const float4*>(src);
    float s = x.x + x.y + x.z + x.w;
    float sq = x.x * x.x + x.y * x.y + x.z * x.z + x.w * x.w;
    for (int m = 1; m < 64; m <<= 1) { s += __shfl_xor(s, m); sq += __shfl_xor(sq, m); }
    float mu = s * (1.f / 256.f);
    float var = sq * (1.f / 256.f) - mu * mu;
    float rstd = rsqrtf(var + LNEPS);
    int k0 = lane * 4;
    float o0 = (x.x - mu) * rstd * gsh[k0 + 0] + bsh[k0 + 0];
    float o1 = (x.y - mu) * rstd * gsh[k0 + 1] + bsh[k0 + 1];
    float o2 = (x.z - mu) * rstd * gsh[k0 + 2] + bsh[k0 + 2];
    float o3 = (x.w - mu) * rstd * gsh[k0 + 3] + bsh[k0 + 3];
    short4v hi, lo;
    hi.x = f2bf(o0); lo.x = f2bf(o0 - bf2f(hi.x));
    hi.y = f2bf(o1); lo.y = f2bf(o1 - bf2f(hi.y));
    hi.z = f2bf(o2); lo.z = f2bf(o2 - bf2f(hi.z));
    hi.w = f2bf(o3); lo.w = f2bf(o3 - bf2f(hi.w));
    *reinterpret_cast<short4v*>(&Ahi[row][k0]) = hi;
    *reinterpret_cast<short4v*>(&Alo[row][k0]) = lo;
  }
  __syncthreads();
  // MFMA: wave -> (m-tile wr, n-half wc)
  const int wr = wv >> 1, wc = wv & 1;
  const int arow = wr * 16 + (lane & 15);
  const int kb = (lane >> 4) * 8;  // k sub-block within 32
  f32x4 acc[4] = {{0.f, 0.f, 0.f, 0.f}, {0.f, 0.f, 0.f, 0.f},
                  {0.f, 0.f, 0.f, 0.f}, {0.f, 0.f, 0.f, 0.f}};
  for (int kk = 0; kk < 8; kk++) {
    short8 ahi = *reinterpret_cast<const short8*>(&Ahi[arow][kk * 32 + kb]);
    short8 alo = *reinterpret_cast<const short8*>(&Alo[arow][kk * 32 + kb]);
#pragma unroll
    for (int nt = 0; nt < 4; nt++) {
      int n = wc * 64 + nt * 16 + (lane & 15);
      short8 bhi = *reinterpret_cast<const short8*>(Whi + (size_t)n * 256 + kk * 32 + kb);
      short8 blo = *reinterpret_cast<const short8*>(Wlo + (size_t)n * 256 + kk * 32 + kb);
      acc[nt] = __builtin_amdgcn_mfma_f32_16x16x32_bf16(ahi, bhi, acc[nt], 0, 0, 0);
      acc[nt] = __builtin_amdgcn_mfma_f32_16x16x32_bf16(alo, bhi, acc[nt], 0, 0, 0);
      acc[nt] = __builtin_amdgcn_mfma_f32_16x16x32_bf16(ahi, blo, acc[nt], 0, 0, 0);
    }
  }
  __syncthreads();  // all A-tile reads done before Zsh overwrites the space
  // Z = acc + bias -> LDS
#pragma unroll
  for (int nt = 0; nt < 4; nt++) {
    int col = wc * 64 + nt * 16 + (lane & 15);
    float bb = b2sh[col];
#pragma unroll
    for (int r = 0; r < 4; r++) {
      int zr = wr * 16 + (lane >> 4) * 4 + r;
      Zsh[zr][col] = acc[nt][r] + bb;
    }
  }
  __syncthreads();
  // segmented reduce by v (rows sorted by v) + boundary atomics
  if (t < 128) {
    float a = 0.f;
    for (int r = 0; r < 32; r++) {
      a += Zsh[r][t];
      if (r == 31 || vs[r + 1] != vs[r]) {
        atomicAdd(&Xv_sum[(size_t)vs[r] * 128 + t], a);
        a = 0.f;
      }
    }
  }
}

// ============================ classifier ============================
__global__ __launch_bounds__(128) void k_cls(
    const float* __restrict__ X, const float* __restrict__ W1,
    const float* __restrict__ b1, const float* __restrict__ lg,
    const float* __restrict__ lb, const float* __restrict__ W2,
    const float* __restrict__ b2, float* __restrict__ out, int N) {
  __shared__ float xr[128];
  int n = blockIdx.x, t = threadIdx.x;
  xr[t] = X[(size_t)n * 128 + t];
  __syncthreads();
  if (t < 64) {
    float a = b1[t];
    for (int k = 0; k < 128; k++) a += xr[k] * W1[k * 64 + t];
    float h = fmaxf(a, 0.f);
    float s = h, sq = h * h;
    for (int m = 1; m < 64; m <<= 1) { s += __shfl_xor(s, m); sq += __shfl_xor(sq, m); }
    float mu = s * (1.f / 64.f);
    float var = sq * (1.f / 64.f) - mu * mu;
    float rstd = rsqrtf(var + LNEPS);
    float hn = (h - mu) * rstd * lg[t] + lb[t];
    float c = hn * W2[t];
    for (int m = 1; m < 64; m <<= 1) c += __shfl_xor(c, m);
    if (t == 0) out[n] = c + b2[0];
  }
}

// ============================ driver ============================
static void run_branch(const float* x_in, const int* v, const int* e,
                       const float* lin_w, const float* lin_b,
                       const float* w1g, const float* w1bn, const float* w1w, const float* w1b,
                       const float* w2g, const float* w2bn,
                       const short* w2hi, const short* w2lo, const float* w2b,
                       const float* wg, const float* wbn, const float* ww, const float* wb,
                       const float* cw1, const float* cb1, const float* cg, const float* cbn,
                       const float* cw2, const float* cb2,
                       float* X, float* X0, float* A, float* B, float* Xe,
                       int* starts_e, int* starts_v, int* cursor, int* bsums,
                       int* v_by_e, int* e_by_v, int* v_sorted,
                       float* out, hipStream_t stream) {
  // CSR by hedge
  hipMemsetAsync(starts_e, 0, (NH + 1) * sizeof(int), stream);
  k_hist<<<(NI + 255) / 256, 256, 0, stream>>>(e, NI, starts_e);
  k_scan1<<<(NH + 1023) / 1024, 1024, 0, stream>>>(starts_e, NH, bsums);
  k_scan2<<<1, 1024, 0, stream>>>(bsums, (NH + 1023) / 1024);
  k_scan3<<<(NH + 255) / 256, 256, 0, stream>>>(starts_e, bsums, NH, NI);
  hipMemsetAsync(cursor, 0, NH * sizeof(int), stream);
  k_fill<<<(NI + 255) / 256, 256, 0, stream>>>(e, v, NI, starts_e, cursor, v_by_e, nullptr);
  k_sort_seg<<<(NH + 255) / 256, 256, 0, stream>>>(starts_e, NH, v_by_e);
  // CSR by node
  hipMemsetAsync(starts_v, 0, (NN + 1) * sizeof(int), stream);
  k_hist<<<(NI + 255) / 256, 256, 0, stream>>>(v, NI, starts_v);
  k_scan1<<<(NN + 1023) / 1024, 1024, 0, stream>>>(starts_v, NN, bsums);
  k_scan2<<<1, 1024, 0, stream>>>(bsums, (NN + 1023) / 1024);
  k_scan3<<<(NN + 255) / 256, 256, 0, stream>>>(starts_v, bsums, NN, NI);
  hipMemsetAsync(cursor, 0, NN * sizeof(int), stream);
  k_fill<<<(NI + 255) / 256, 256, 0, stream>>>(v, e, NI, starts_v, cursor, e_by_v, v_sorted);
  k_sort_seg<<<(NN + 255) / 256, 256, 0, stream>>>(starts_v, NN, e_by_v);
  // input projection (+relu), duplicated into X and X0
  k_gemm_rows<FIN, 16, true><<<NN / 16, 128, 0, stream>>>(x_in, lin_w, lin_b, X, X0, NN);
  for (int layer = 0; layer < 2; ++layer) {
    k_ln128<<<NN / 4, 256, 0, stream>>>(X, w1g, w1bn, A, NN);
    k_gemm_rows<HID, 16, false><<<NN / 16, 128, 0, stream>>>(A, w1w, w1b, B, nullptr, NN);
    k_xe<<<NH / 4, 256, 0, stream>>>(B, starts_e, v_by_e, Xe, NH);
    hipMemsetAsync(A, 0, (size_t)NN * 128 * sizeof(float), stream);  // A becomes Xv_sum
    k_w2<<<NI / 32, 256, 0, stream>>>(X, Xe, v_sorted, e_by_v, w2g, w2bn, w2hi, w2lo, w2b, A);
    k_blend_ln<<<NN / 4, 256, 0, stream>>>(A, starts_v, X0, wg, wbn, B, NN);
    k_gemm_rows<HID, 16, true><<<NN / 16, 128, 0, stream>>>(B, ww, wb, X, nullptr, NN);
  }
  k_cls<<<NN, 128, 0, stream>>>(X, cw1, cb1, cg, cbn, cw2, cb2, out, NN);
}

extern "C" void kernel_launch(void* const* d_in, const int* in_sizes, int n_in,
                              void* d_out, int out_size, void* d_ws, size_t ws_size,
                              hipStream_t stream) {
  (void)in_sizes; (void)n_in; (void)out_size; (void)ws_size;
  const float* x1 = (const float*)d_in[0];
  const int* v1 = (const int*)d_in[1];
  const int* e1 = (const int*)d_in[2];
  const float* x2 = (const float*)d_in[3];
  const int* v2 = (const int*)d_in[4];
  const int* e2 = (const int*)d_in[5];
  const float* lin_w = (const float*)d_in[6];
  const float* lin_b = (const float*)d_in[7];
  const float* w1g = (const float*)d_in[8];
  const float* w1bn = (const float*)d_in[9];
  const float* w1w = (const float*)d_in[10];
  const float* w1b = (const float*)d_in[11];
  const float* w2g = (const float*)d_in[12];
  const float* w2bn = (const float*)d_in[13];
  const float* w2w = (const float*)d_in[14];
  const float* w2b = (const float*)d_in[15];
  const float* wg = (const float*)d_in[16];
  const float* wbn = (const float*)d_in[17];
  const float* ww = (const float*)d_in[18];
  const float* wb = (const float*)d_in[19];
  const float* cw1 = (const float*)d_in[20];
  const float* cb1 = (const float*)d_in[21];
  const float* cg = (const float*)d_in[22];
  const float* cbn = (const float*)d_in[23];
  const float* cw2 = (const float*)d_in[24];
  const float* cb2 = (const float*)d_in[25];

  char* p = (char*)d_ws;
  auto alloc = [&](size_t bytes) {
    char* r = p;
    p += (bytes + 255) & ~(size_t)255;
    return r;
  };
  float* X = (float*)alloc((size_t)NN * 128 * 4);
  float* X0 = (float*)alloc((size_t)NN * 128 * 4);
  float* A = (float*)alloc((size_t)NN * 128 * 4);   // LN scratch / Xv_sum
  float* B = (float*)alloc((size_t)NN * 128 * 4);
  float* Xe = (float*)alloc((size_t)NH * 128 * 4);
  int* starts_e = (int*)alloc((NH + 1) * 4);
  int* starts_v = (int*)alloc((NN + 1) * 4);
  int* cursor = (int*)alloc(NH * 4);
  int* bsums = (int*)alloc(1024 * 4);
  int* v_by_e = (int*)alloc((size_t)NI * 4);
  int* e_by_v = (int*)alloc((size_t)NI * 4);
  int* v_sorted = (int*)alloc((size_t)NI * 4);
  short* W2hi = (short*)alloc((size_t)256 * 128 * 2);
  short* W2lo = (short*)alloc((size_t)256 * 128 * 2);

  // one-time per launch: transpose+convert w2 weights to bf16 hi/lo [n][k]
  k_cvt_w2<<<128, 256, 0, stream>>>(w2w, W2hi, W2lo);

  float* out = (float*)d_out;
  run_branch(x1, v1, e1, lin_w, lin_b, w1g, w1bn, w1w, w1b, w2g, w2bn, W2hi, W2lo, w2b,
             wg, wbn, ww, wb, cw1, cb1, cg, cbn, cw2, cb2,
             X, X0, A, B, Xe, starts_e, starts_v, cursor, bsums,
             v_by_e, e_by_v, v_sorted, out, stream);
  run_branch(x2, v2, e2, lin_w, lin_b, w1g, w1bn, w1w, w1b, w2g, w2bn, W2hi, W2lo, w2b,
             wg, wbn, ww, wb, cw1, cb1, cg, cbn, cw2, cb2,
             X, X0, A, B, Xe, starts_e, starts_v, cursor, bsums,
             v_by_e, e_by_v, v_sorted, out + NN, stream);
}

// Round 4
// 2424.924 us; speedup vs baseline: 1.7499x; 1.6440x over previous
//
#include <hip/hip_runtime.h>

#define NN 50000
#define NH 100000
#define NI 600000
#define FIN 512
#define HID 128
#define LNEPS 1e-5f

// ============================ CSR build ============================
__global__ void k_hist(const int* __restrict__ idx, int n, int* __restrict__ deg) {
  int i = blockIdx.x * 256 + threadIdx.x;
  if (i < n) atomicAdd(&deg[idx[i]], 1);
}

__global__ __launch_bounds__(1024) void k_scan1(int* __restrict__ data, int m,
                                                int* __restrict__ bsums) {
  __shared__ int sh[1024];
  int tid = threadIdx.x;
  int i = blockIdx.x * 1024 + tid;
  int v = (i < m) ? data[i] : 0;
  sh[tid] = v;
  __syncthreads();
  for (int off = 1; off < 1024; off <<= 1) {
    int tv = (tid >= off) ? sh[tid - off] : 0;
    __syncthreads();
    sh[tid] += tv;
    __syncthreads();
  }
  if (i < m) data[i] = sh[tid] - v;  // exclusive
  if (tid == 1023) bsums[blockIdx.x] = sh[1023];
}

__global__ __launch_bounds__(1024) void k_scan2(int* __restrict__ bsums, int nb) {
  __shared__ int sh[1024];
  int tid = threadIdx.x;
  int v = (tid < nb) ? bsums[tid] : 0;
  sh[tid] = v;
  __syncthreads();
  for (int off = 1; off < 1024; off <<= 1) {
    int tv = (tid >= off) ? sh[tid - off] : 0;
    __syncthreads();
    sh[tid] += tv;
    __syncthreads();
  }
  if (tid < nb) bsums[tid] = sh[tid] - v;
}

__global__ void k_scan3(int* __restrict__ data, const int* __restrict__ bsums,
                        int m, int total) {
  int i = blockIdx.x * 256 + threadIdx.x;
  if (i < m) data[i] += bsums[i >> 10];
  if (i == 0) data[m] = total;
}

__global__ void k_fill(const int* __restrict__ key, const int* __restrict__ oth, int n,
                       const int* __restrict__ starts, int* __restrict__ cursor,
                       int* __restrict__ out_oth) {
  int i = blockIdx.x * 256 + threadIdx.x;
  if (i >= n) return;
  int k = key[i];
  int pos = starts[k] + atomicAdd(&cursor[k], 1);
  out_oth[pos] = oth[i];
}

// Sort each CSR segment ascending -> deterministic order every replay
// (arrival order from k_fill's atomics is not replay-stable).
__global__ void k_sort_seg(const int* __restrict__ starts, int nseg,
                           int* __restrict__ vals) {
  int seg = blockIdx.x * 256 + threadIdx.x;
  if (seg >= nseg) return;
  int s = starts[seg], e = starts[seg + 1];
  int d = e - s;
  if (d <= 1) return;
  if (d <= 48) {
    int buf[48];
    for (int i = 0; i < d; i++) buf[i] = vals[s + i];
    for (int i = 1; i < d; i++) {
      int key = buf[i], j = i - 1;
      while (j >= 0 && buf[j] > key) { buf[j + 1] = buf[j]; j--; }
      buf[j + 1] = key;
    }
    for (int i = 0; i < d; i++) vals[s + i] = buf[i];
  } else {
    for (int i = s + 1; i < e; i++) {
      int key = vals[i], j = i - 1;
      while (j >= s && vals[j] > key) { vals[j + 1] = vals[j]; j--; }
      vals[j + 1] = key;
    }
  }
}

// ============================ W2 precompute ============================
// W2g[k][n] = g2[k] * W2[k][n]  (256 x 128)
__global__ void k_prep_w2g(const float* __restrict__ W2, const float* __restrict__ g2,
                           float* __restrict__ W2g) {
  int i = blockIdx.x * 256 + threadIdx.x;
  if (i >= 256 * 128) return;
  int k = i >> 7;
  W2g[i] = g2[k] * W2[i];
}

// s_g[n] = sum_k g2[k]*W2[k][n];  c0[n] = sum_k b2[k]*W2[k][n] + bias2[n]
__global__ __launch_bounds__(128) void k_prep_sgc0(
    const float* __restrict__ W2, const float* __restrict__ g2,
    const float* __restrict__ b2, const float* __restrict__ bias2,
    float* __restrict__ s_g, float* __restrict__ c0) {
  int t = threadIdx.x;
  float sg = 0.f, cc = 0.f;
  for (int k = 0; k < 256; k++) {
    float w = W2[k * 128 + t];
    sg += g2[k] * w;
    cc += b2[k] * w;
  }
  s_g[t] = sg;
  c0[t] = cc + bias2[t];
}

// ============================ row GEMMs (fp32 VALU) ============================
// A (N x K) @ W (K x 128) [+ bias] -> out (N x 128); optional relu, dup store.
// In-place safe (out==A): block reads its 16 rows fully into LDS before writing.
template <int K, int TM, bool RELU>
__global__ __launch_bounds__(128) void k_gemm_rows(
    const float* __restrict__ A, const float* __restrict__ W,
    const float* __restrict__ bias, float* __restrict__ out,
    float* __restrict__ out2, int N) {
  __shared__ float Ash[TM][K];
  const int t = threadIdx.x;
  const int r0 = blockIdx.x * TM;
  const int nf4 = TM * K / 4;
  const float4* Ag = reinterpret_cast<const float4*>(A + (size_t)r0 * K);
  float4* As4 = reinterpret_cast<float4*>(&Ash[0][0]);
  for (int f = t; f < nf4; f += 128) As4[f] = Ag[f];
  __syncthreads();
  float acc[TM];
#pragma unroll
  for (int r = 0; r < TM; r++) acc[r] = 0.f;
  for (int k = 0; k < K; k++) {
    float wv = W[k * 128 + t];
#pragma unroll
    for (int r = 0; r < TM; r++) acc[r] += Ash[r][k] * wv;
  }
  float b = bias ? bias[t] : 0.f;
  for (int r = 0; r < TM; r++) {
    float v = acc[r] + b;
    if (RELU) v = fmaxf(v, 0.f);
    out[(size_t)(r0 + r) * 128 + t] = v;
    if (out2) out2[(size_t)(r0 + r) * 128 + t] = v;
  }
}

// ============================ LayerNorm (width 128) + raw row stats ============================
__global__ __launch_bounds__(256) void k_ln128_stats(
    const float* __restrict__ in, const float* __restrict__ g,
    const float* __restrict__ b, float* __restrict__ out,
    float* __restrict__ sn, float* __restrict__ qn, int N) {
  int wave = threadIdx.x >> 6, lane = threadIdx.x & 63;
  int row = blockIdx.x * 4 + wave;
  if (row >= N) return;
  float2 x = reinterpret_cast<const float2*>(in + (size_t)row * 128)[lane];
  float s = x.x + x.y, sq = x.x * x.x + x.y * x.y;
  for (int m = 1; m < 64; m <<= 1) { s += __shfl_xor(s, m); sq += __shfl_xor(sq, m); }
  if (lane == 0) { sn[row] = s; qn[row] = sq; }  // raw sums over 128 elems
  float mu = s * (1.f / 128.f);
  float var = sq * (1.f / 128.f) - mu * mu;
  float rstd = rsqrtf(var + LNEPS);
  float2 gg = reinterpret_cast<const float2*>(g)[lane];
  float2 bb = reinterpret_cast<const float2*>(b)[lane];
  float2 o;
  o.x = (x.x - mu) * rstd * gg.x + bb.x;
  o.y = (x.y - mu) * rstd * gg.y + bb.y;
  reinterpret_cast<float2*>(out + (size_t)row * 128)[lane] = o;
}

// ============================ hedge scatter-mean + row stats ============================
__global__ __launch_bounds__(256) void k_xe_stats(
    const float* __restrict__ Y, const int* __restrict__ starts,
    const int* __restrict__ vlist, float* __restrict__ Xe,
    float* __restrict__ se, float* __restrict__ qe, int M) {
  int wave = threadIdx.x >> 6, lane = threadIdx.x & 63;
  int m = blockIdx.x * 4 + wave;
  if (m >= M) return;
  int s = starts[m], e = starts[m + 1];
  float2 acc = {0.f, 0.f};
  for (int j = s; j < e; j++) {
    int vv = vlist[j];
    float2 val = reinterpret_cast<const float2*>(Y + (size_t)vv * 128)[lane];
    acc.x += val.x;
    acc.y += val.y;
  }
  int d = e - s;
  float inv = d > 0 ? 1.f / (float)d : 0.f;
  float2 o = {acc.x * inv, acc.y * inv};
  reinterpret_cast<float2*>(Xe + (size_t)m * 128)[lane] = o;
  float ss = o.x + o.y, qq = o.x * o.x + o.y * o.y;
  for (int mm = 1; mm < 64; mm <<= 1) { ss += __shfl_xor(ss, mm); qq += __shfl_xor(qq, mm); }
  if (lane == 0) { se[m] = ss; qe[m] = qq; }
}

// ============================ per-node combine: W2-mean + blend + LN ============================
// Xv[v,:] = (1/deg) * ( suma*U[v,:] + sum_p a_p*V[e_p,:] - sumb*s_g[:] ) + c0[:]
// with a_p = rstd_p, b_p = mu_p*rstd_p from per-node/per-hedge raw sums.
// Then X = 0.5*Xv + 0.5*X0, LN(wg,wbn) -> outB. One wave per node, no atomics.
__global__ __launch_bounds__(256) void k_node(
    const float* __restrict__ U, const float* __restrict__ V,
    const float* __restrict__ X0, const int* __restrict__ starts_v,
    const int* __restrict__ e_by_v, const float* __restrict__ sn,
    const float* __restrict__ qn, const float* __restrict__ se,
    const float* __restrict__ qe, const float* __restrict__ s_g,
    const float* __restrict__ c0, const float* __restrict__ wg,
    const float* __restrict__ wbn, float* __restrict__ outB, int N) {
  int wave = threadIdx.x >> 6, lane = threadIdx.x & 63;
  int v = blockIdx.x * 4 + wave;
  if (v >= N) return;
  int s = starts_v[v], e = starts_v[v + 1];
  float svn = sn[v], qvn = qn[v];
  float2 acc = {0.f, 0.f};
  float suma = 0.f, sumb = 0.f;
  for (int j = s; j < e; j++) {
    int ee = e_by_v[j];
    float mu = (svn + se[ee]) * (1.f / 256.f);
    float e2 = (qvn + qe[ee]) * (1.f / 256.f);
    float rstd = rsqrtf(e2 - mu * mu + LNEPS);
    suma += rstd;
    sumb += mu * rstd;
    float2 vv = reinterpret_cast<const float2*>(V + (size_t)ee * 128)[lane];
    acc.x += rstd * vv.x;
    acc.y += rstd * vv.y;
  }
  int deg = e - s;
  float inv = deg > 0 ? 1.f / (float)deg : 0.f;
  float2 uu = reinterpret_cast<const float2*>(U + (size_t)v * 128)[lane];
  float2 sg = reinterpret_cast<const float2*>(s_g)[lane];
  float2 cc = reinterpret_cast<const float2*>(c0)[lane];
  float xvx = deg > 0 ? (suma * uu.x + acc.x - sumb * sg.x) * inv + cc.x : 0.f;
  float xvy = deg > 0 ? (suma * uu.y + acc.y - sumb * sg.y) * inv + cc.y : 0.f;
  float2 x0 = reinterpret_cast<const float2*>(X0 + (size_t)v * 128)[lane];
  float ax = 0.5f * xvx + 0.5f * x0.x;
  float ay = 0.5f * xvy + 0.5f * x0.y;
  float ss = ax + ay, qq = ax * ax + ay * ay;
  for (int m = 1; m < 64; m <<= 1) { ss += __shfl_xor(ss, m); qq += __shfl_xor(qq, m); }
  float mu = ss * (1.f / 128.f);
  float var = qq * (1.f / 128.f) - mu * mu;
  float rstd = rsqrtf(var + LNEPS);
  float2 gg = reinterpret_cast<const float2*>(wg)[lane];
  float2 bb = reinterpret_cast<const float2*>(wbn)[lane];
  float2 o;
  o.x = (ax - mu) * rstd * gg.x + bb.x;
  o.y = (ay - mu) * rstd * gg.y + bb.y;
  reinterpret_cast<float2*>(outB + (size_t)v * 128)[lane] = o;
}

// ============================ classifier ============================
__global__ __launch_bounds__(128) void k_cls(
    const float* __restrict__ X, const float* __restrict__ W1,
    const float* __restrict__ b1, const float* __restrict__ lg,
    const float* __restrict__ lb, const float* __restrict__ W2,
    const float* __restrict__ b2, float* __restrict__ out, int N) {
  __shared__ float xr[128];
  int n = blockIdx.x, t = threadIdx.x;
  xr[t] = X[(size_t)n * 128 + t];
  __syncthreads();
  if (t < 64) {
    float a = b1[t];
    for (int k = 0; k < 128; k++) a += xr[k] * W1[k * 64 + t];
    float h = fmaxf(a, 0.f);
    float s = h, sq = h * h;
    for (int m = 1; m < 64; m <<= 1) { s += __shfl_xor(s, m); sq += __shfl_xor(sq, m); }
    float mu = s * (1.f / 64.f);
    float var = sq * (1.f / 64.f) - mu * mu;
    float rstd = rsqrtf(var + LNEPS);
    float hn = (h - mu) * rstd * lg[t] + lb[t];
    float c = hn * W2[t];
    for (int m = 1; m < 64; m <<= 1) c += __shfl_xor(c, m);
    if (t == 0) out[n] = c + b2[0];
  }
}

// ============================ driver ============================
static void run_branch(const float* x_in, const int* v, const int* e,
                       const float* lin_w, const float* lin_b,
                       const float* w1g, const float* w1bn, const float* w1w, const float* w1b,
                       const float* W2g, const float* s_g, const float* c0,
                       const float* wg, const float* wbn, const float* ww, const float* wb,
                       const float* cw1, const float* cb1, const float* cg, const float* cbn,
                       const float* cw2, const float* cb2,
                       float* X, float* X0, float* A, float* B, float* Xe,
                       float* sn, float* qn, float* se, float* qe,
                       int* starts_e, int* starts_v, int* cursor, int* bsums,
                       int* v_by_e, int* e_by_v,
                       float* out, hipStream_t stream) {
  // CSR by hedge
  hipMemsetAsync(starts_e, 0, (NH + 1) * sizeof(int), stream);
  k_hist<<<(NI + 255) / 256, 256, 0, stream>>>(e, NI, starts_e);
  k_scan1<<<(NH + 1023) / 1024, 1024, 0, stream>>>(starts_e, NH, bsums);
  k_scan2<<<1, 1024, 0, stream>>>(bsums, (NH + 1023) / 1024);
  k_scan3<<<(NH + 255) / 256, 256, 0, stream>>>(starts_e, bsums, NH, NI);
  hipMemsetAsync(cursor, 0, NH * sizeof(int), stream);
  k_fill<<<(NI + 255) / 256, 256, 0, stream>>>(e, v, NI, starts_e, cursor, v_by_e);
  k_sort_seg<<<(NH + 255) / 256, 256, 0, stream>>>(starts_e, NH, v_by_e);
  // CSR by node
  hipMemsetAsync(starts_v, 0, (NN + 1) * sizeof(int), stream);
  k_hist<<<(NI + 255) / 256, 256, 0, stream>>>(v, NI, starts_v);
  k_scan1<<<(NN + 1023) / 1024, 1024, 0, stream>>>(starts_v, NN, bsums);
  k_scan2<<<1, 1024, 0, stream>>>(bsums, (NN + 1023) / 1024);
  k_scan3<<<(NN + 255) / 256, 256, 0, stream>>>(starts_v, bsums, NN, NI);
  hipMemsetAsync(cursor, 0, NN * sizeof(int), stream);
  k_fill<<<(NI + 255) / 256, 256, 0, stream>>>(v, e, NI, starts_v, cursor, e_by_v);
  k_sort_seg<<<(NN + 255) / 256, 256, 0, stream>>>(starts_v, NN, e_by_v);
  // input projection (+relu), duplicated into X and X0
  k_gemm_rows<FIN, 16, true><<<NN / 16, 128, 0, stream>>>(x_in, lin_w, lin_b, X, X0, NN);
  for (int layer = 0; layer < 2; ++layer) {
    k_ln128_stats<<<NN / 4, 256, 0, stream>>>(X, w1g, w1bn, A, sn, qn, NN);
    k_gemm_rows<HID, 16, false><<<NN / 16, 128, 0, stream>>>(A, w1w, w1b, B, nullptr, NN);
    k_xe_stats<<<NH / 4, 256, 0, stream>>>(B, starts_e, v_by_e, Xe, se, qe, NH);
    // U = X @ W2g_top   (in-place over X; X is dead afterwards)
    k_gemm_rows<HID, 16, false><<<NN / 16, 128, 0, stream>>>(X, W2g, nullptr, X, nullptr, NN);
    // V = Xe @ W2g_bot  (in-place over Xe)
    k_gemm_rows<HID, 16, false><<<NH / 16, 128, 0, stream>>>(Xe, W2g + 128 * 128, nullptr, Xe, nullptr, NH);
    k_node<<<NN / 4, 256, 0, stream>>>(X, Xe, X0, starts_v, e_by_v, sn, qn, se, qe,
                                       s_g, c0, wg, wbn, B, NN);
    k_gemm_rows<HID, 16, true><<<NN / 16, 128, 0, stream>>>(B, ww, wb, X, nullptr, NN);
  }
  k_cls<<<NN, 128, 0, stream>>>(X, cw1, cb1, cg, cbn, cw2, cb2, out, NN);
}

extern "C" void kernel_launch(void* const* d_in, const int* in_sizes, int n_in,
                              void* d_out, int out_size, void* d_ws, size_t ws_size,
                              hipStream_t stream) {
  (void)in_sizes; (void)n_in; (void)out_size; (void)ws_size;
  const float* x1 = (const float*)d_in[0];
  const int* v1 = (const int*)d_in[1];
  const int* e1 = (const int*)d_in[2];
  const float* x2 = (const float*)d_in[3];
  const int* v2 = (const int*)d_in[4];
  const int* e2 = (const int*)d_in[5];
  const float* lin_w = (const float*)d_in[6];
  const float* lin_b = (const float*)d_in[7];
  const float* w1g = (const float*)d_in[8];
  const float* w1bn = (const float*)d_in[9];
  const float* w1w = (const float*)d_in[10];
  const float* w1b = (const float*)d_in[11];
  const float* w2g = (const float*)d_in[12];
  const float* w2bn = (const float*)d_in[13];
  const float* w2w = (const float*)d_in[14];
  const float* w2b = (const float*)d_in[15];
  const float* wg = (const float*)d_in[16];
  const float* wbn = (const float*)d_in[17];
  const float* ww = (const float*)d_in[18];
  const float* wb = (const float*)d_in[19];
  const float* cw1 = (const float*)d_in[20];
  const float* cb1 = (const float*)d_in[21];
  const float* cg = (const float*)d_in[22];
  const float* cbn = (const float*)d_in[23];
  const float* cw2 = (const float*)d_in[24];
  const float* cb2 = (const float*)d_in[25];

  char* p = (char*)d_ws;
  auto alloc = [&](size_t bytes) {
    char* r = p;
    p += (bytes + 255) & ~(size_t)255;
    return r;
  };
  float* X = (float*)alloc((size_t)NN * 128 * 4);   // also holds U in-place
  float* X0 = (float*)alloc((size_t)NN * 128 * 4);
  float* A = (float*)alloc((size_t)NN * 128 * 4);
  float* B = (float*)alloc((size_t)NN * 128 * 4);
  float* Xe = (float*)alloc((size_t)NH * 128 * 4);  // also holds V in-place
  float* sn = (float*)alloc((size_t)NN * 4);
  float* qn = (float*)alloc((size_t)NN * 4);
  float* se = (float*)alloc((size_t)NH * 4);
  float* qe = (float*)alloc((size_t)NH * 4);
  int* starts_e = (int*)alloc((NH + 1) * 4);
  int* starts_v = (int*)alloc((NN + 1) * 4);
  int* cursor = (int*)alloc(NH * 4);
  int* bsums = (int*)alloc(1024 * 4);
  int* v_by_e = (int*)alloc((size_t)NI * 4);
  int* e_by_v = (int*)alloc((size_t)NI * 4);
  float* W2g = (float*)alloc((size_t)256 * 128 * 4);
  float* s_g = (float*)alloc(128 * 4);
  float* c0 = (float*)alloc(128 * 4);

  // one-time per launch: W2 precomputation (shared by both branches)
  k_prep_w2g<<<128, 256, 0, stream>>>(w2w, w2g, W2g);
  k_prep_sgc0<<<1, 128, 0, stream>>>(w2w, w2g, w2bn, w2b, s_g, c0);

  float* out = (float*)d_out;
  run_branch(x1, v1, e1, lin_w, lin_b, w1g, w1bn, w1w, w1b, W2g, s_g, c0,
             wg, wbn, ww, wb, cw1, cb1, cg, cbn, cw2, cb2,
             X, X0, A, B, Xe, sn, qn, se, qe, starts_e, starts_v, cursor, bsums,
             v_by_e, e_by_v, out, stream);
  run_branch(x2, v2, e2, lin_w, lin_b, w1g, w1bn, w1w, w1b, W2g, s_g, c0,
             wg, wbn, ww, wb, cw1, cb1, cg, cbn, cw2, cb2,
             X, X0, A, B, Xe, sn, qn, se, qe, starts_e, starts_v, cursor, bsums,
             v_by_e, e_by_v, out + NN, stream);
}